// Round 16
// baseline (91.023 us; speedup 1.0000x reference)
//
#include <hip/hip_runtime.h>

// LTPE: y(p) = x(p) - sum_j w_j * x(p + off_j), zero-padded borders,
// then instance-norm over HxW per image: (y - mean) * rsqrt(var + 4e-5).
// (The reference's out = 0.5*y + 0.5; instance norm is affine-invariant,
//  with eps folding 1e-5 -> 4e-5.)
//
// Round 16 structure: pass 1 = stencil, writes y (f32, PLAIN stores ->
// L2/L3-allocated) directly into d_out + stats partials. Pass 2 = pure
// in-place elementwise normalize out = (out-mean)*scale: reads its own
// just-written L3-resident lines, re-dirties them (writeback
// cancellation), zero dependency chains. Round-9 evidence: elementwise
// RMW class ran ~2x faster (12.8 TB/s combined) than the stencil class
// (6.5 TB/s). No bf16 anywhere; all f32.

#define HH 1024
#define WW 1024
#define HW (HH * WW)
#define NIMG 32
#define NBLK1 64                 // pass-1 blocks per image (stencil)
#define RPB1 (HH / NBLK1)        // 16 rows per block
#define NBLK2 64                 // pass-2 blocks per image (elementwise)
#define EPB2 (HW / NBLK2)        // 16384 elements per pass-2 block
#define TPB 256                  // = WW/4 float4 columns per row

typedef float vfloat4 __attribute__((ext_vector_type(4)));
typedef float vfloat4u __attribute__((ext_vector_type(4), aligned(4)));
typedef float vfloat2u __attribute__((ext_vector_type(2), aligned(4)));

// weights: j=0..7 -> 2^j/255, offsets (dy,dx):
// j0 (0,-1), j1 (1,-1), j2 (1,0), j3 (1,1), j4 (0,1), j5 (-1,1), j6 (-1,0), j7 (-1,-1)
__device__ __forceinline__ void compute_y(const float* up, const float* mid,
                                          const float* dn, float* y) {
    const float w0 = 1.f / 255.f,  w1 = 2.f / 255.f,  w2 = 4.f / 255.f,
                w3 = 8.f / 255.f,  w4 = 16.f / 255.f, w5 = 32.f / 255.f,
                w6 = 64.f / 255.f, w7 = 128.f / 255.f;
#pragma unroll
    for (int k = 0; k < 4; ++k) {
        float s = w0 * mid[k] + w4 * mid[k + 2]
                + w1 * dn[k]  + w2 * dn[k + 1] + w3 * dn[k + 2]
                + w7 * up[k]  + w6 * up[k + 1] + w5 * up[k + 2];
        y[k] = mid[k + 1] - s;
    }
}

// 6-float window [4c-1 .. 4c+4] in 2 VMEM ops; edge lanes fixed by selects.
__device__ __forceinline__ void load_row_g(const float* __restrict__ base,
                                           int r, int c, float* buf) {
    if (r < 0 || r >= HH) {
#pragma unroll
        for (int k = 0; k < 6; ++k) buf[k] = 0.f;
        return;
    }
    const float* p = base + (size_t)r * WW + 4 * c;
    const bool notfirst = (c > 0);
    const bool notlast = (c < TPB - 1);
    const vfloat4u a = *reinterpret_cast<const vfloat4u*>(p - (notfirst ? 1 : 0));
    const vfloat2u b = *reinterpret_cast<const vfloat2u*>(p + (notlast ? 3 : 2));
    buf[0] = notfirst ? a.x : 0.f;
    buf[1] = notfirst ? a.y : a.x;
    buf[2] = notfirst ? a.z : a.y;
    buf[3] = notfirst ? a.w : a.z;
    buf[4] = notlast ? b.x : b.y;
    buf[5] = notlast ? b.y : 0.f;
}

// -------- pass 1: stencil -> y into d_out (plain f32) + stats partials --------
__global__ __launch_bounds__(TPB) void ltpe_stencil(const float* __restrict__ x,
                                                    float* __restrict__ partials,
                                                    float* __restrict__ out) {
    const int img = blockIdx.x / NBLK1;
    const int blk = blockIdx.x % NBLK1;
    const int c = threadIdx.x;
    const float* base = x + (size_t)img * HW;
    float* obase = out + (size_t)img * HW;
    const int r0 = blk * RPB1;

    // rolling 4-row register pipeline (2-deep prefetch), fully unrolled
    float buf[4][6];
    load_row_g(base, r0 - 1, c, buf[0]);
    load_row_g(base, r0,     c, buf[1]);
    load_row_g(base, r0 + 1, c, buf[2]);
    load_row_g(base, r0 + 2, c, buf[3]);

    float s = 0.f, ss = 0.f;
#pragma unroll
    for (int i = 0; i < RPB1; ++i) {
        const int r = r0 + i;
        float y[4];
        compute_y(buf[i & 3], buf[(i + 1) & 3], buf[(i + 2) & 3], y);
#pragma unroll
        for (int k = 0; k < 4; ++k) { s += y[k]; ss = fmaf(y[k], y[k], ss); }
        vfloat4 o;
        o.x = y[0]; o.y = y[1]; o.z = y[2]; o.w = y[3];
        // PLAIN store: allocate y in L2/L3 so pass 2 reads are cache hits
        reinterpret_cast<vfloat4*>(obase + (size_t)r * WW)[c] = o;
        if (i + 2 < RPB1)  // row r+3 serves as dn in iter i+2
            load_row_g(base, r + 3, c, buf[i & 3]);
    }

    // block reduction: wave64 shuffle, then LDS across 4 waves
#pragma unroll
    for (int off = 32; off > 0; off >>= 1) {
        s += __shfl_down(s, off);
        ss += __shfl_down(ss, off);
    }
    __shared__ float sh[8];
    const int wave = threadIdx.x >> 6;
    const int lane = threadIdx.x & 63;
    if (lane == 0) { sh[wave] = s; sh[4 + wave] = ss; }
    __syncthreads();
    if (threadIdx.x == 0) {
        partials[img * NBLK1 + blk] = sh[0] + sh[1] + sh[2] + sh[3];
        partials[NIMG * NBLK1 + img * NBLK1 + blk] = sh[4] + sh[5] + sh[6] + sh[7];
    }
}

// -------- pass 2: in-place elementwise normalize (L3-hot, no deps) --------
__global__ __launch_bounds__(TPB) void ltpe_norm_ip(float* __restrict__ out,
                                                    const float* __restrict__ partials) {
    const int img = blockIdx.x / NBLK2;
    const int blk = blockIdx.x % NBLK2;

    // redundant per-block final reduce of this image's 64 partials (one wave)
    __shared__ float sh_stats[2];
    if (threadIdx.x < 64) {
        const int lane = threadIdx.x;
        double S = (double)partials[img * NBLK1 + lane];
        double SS = (double)partials[NIMG * NBLK1 + img * NBLK1 + lane];
#pragma unroll
        for (int off = 32; off > 0; off >>= 1) {
            S += __shfl_down(S, off);
            SS += __shfl_down(SS, off);
        }
        if (lane == 0) {
            const double N = (double)HW;
            const double m = S / N;
            const double var = SS / N - m * m;
            sh_stats[0] = (float)m;
            sh_stats[1] = (float)(1.0 / sqrt(var + 4e-5)); // 4*eps folds the 0.5
        }
    }
    __syncthreads();
    const float mean = sh_stats[0];
    const float scale = sh_stats[1];
    const float bias = -mean * scale;

    float* p = out + (size_t)img * HW + (size_t)blk * EPB2;

#pragma unroll
    for (int i = 0; i < EPB2 / (TPB * 8); ++i) {  // 8 iterations, 8 floats/thread
        const int idx = i * TPB * 8 + threadIdx.x * 8;
        vfloat4 a = *reinterpret_cast<vfloat4*>(p + idx);
        vfloat4 b = *reinterpret_cast<vfloat4*>(p + idx + 4);
        a.x = fmaf(a.x, scale, bias);
        a.y = fmaf(a.y, scale, bias);
        a.z = fmaf(a.z, scale, bias);
        a.w = fmaf(a.w, scale, bias);
        b.x = fmaf(b.x, scale, bias);
        b.y = fmaf(b.y, scale, bias);
        b.z = fmaf(b.z, scale, bias);
        b.w = fmaf(b.w, scale, bias);
        *reinterpret_cast<vfloat4*>(p + idx) = a;       // re-dirty same lines:
        *reinterpret_cast<vfloat4*>(p + idx + 4) = b;   // writeback cancellation
    }
}

extern "C" void kernel_launch(void* const* d_in, const int* in_sizes, int n_in,
                              void* d_out, int out_size, void* d_ws, size_t ws_size,
                              hipStream_t stream) {
    const float* x = (const float*)d_in[0];
    float* out = (float*)d_out;
    float* partials = (float*)d_ws; // [NIMG*NBLK1 sums][NIMG*NBLK1 sumsqs]

    ltpe_stencil<<<NIMG * NBLK1, TPB, 0, stream>>>(x, partials, out);
    ltpe_norm_ip<<<NIMG * NBLK2, TPB, 0, stream>>>(out, partials);
}

// Round 17
// 70.317 us; speedup vs baseline: 1.2945x; 1.2945x over previous
//
#include <hip/hip_runtime.h>

// LTPE: y(p) = x(p) - sum_j w_j * x(p + off_j), zero-padded borders,
// then instance-norm over HxW per image: (y - mean) * rsqrt(var + 4e-5).
// (The reference's out = 0.5*y + 0.5; instance norm is affine-invariant,
//  with eps folding 1e-5 -> 4e-5.)
//
// R11 two-kernel recompute skeleton (69.7us best). Round-17 experiment:
// prefetch DEPTH 2 -> 4 (ring-8 row buffers, 7 rows issued in prologue,
// steady-state 4 row-loads outstanding per wave). R16 measured the
// stencil class at 2.7 TB/s with VALU 12% / occ 35% -> stall-bound;
// outstanding-bytes arithmetic says depth-2 (~3KB/wave) is marginal vs
// the ~9KB needed to cover ~900cy HBM latency at the per-SIMD BW share.
// Row q lives in slot (q - r0 + 1) & 7. Iter i consumes slots i,i+1,i+2
// (rows r-1,r,r+1) and prefetches row r+6 into slot (i-1)&7 (just freed).

#define HH 1024
#define WW 1024
#define HW (HH * WW)
#define NIMG 32
#define NBLK1 64                 // pass-1 blocks per image (pure read)
#define RPB1 (HH / NBLK1)        // 16 rows per block
#define NBLK2 32                 // pass-2 blocks per image (read + nt store)
#define RPB2 (HH / NBLK2)        // 32 rows per block
#define TPB 256                  // = WW/4 float4 columns per row

typedef float vfloat4 __attribute__((ext_vector_type(4)));
typedef float vfloat4u __attribute__((ext_vector_type(4), aligned(4)));
typedef float vfloat2u __attribute__((ext_vector_type(2), aligned(4)));

// weights: j=0..7 -> 2^j/255, offsets (dy,dx):
// j0 (0,-1), j1 (1,-1), j2 (1,0), j3 (1,1), j4 (0,1), j5 (-1,1), j6 (-1,0), j7 (-1,-1)
__device__ __forceinline__ void compute_y(const float* up, const float* mid,
                                          const float* dn, float* y) {
    const float w0 = 1.f / 255.f,  w1 = 2.f / 255.f,  w2 = 4.f / 255.f,
                w3 = 8.f / 255.f,  w4 = 16.f / 255.f, w5 = 32.f / 255.f,
                w6 = 64.f / 255.f, w7 = 128.f / 255.f;
#pragma unroll
    for (int k = 0; k < 4; ++k) {
        float s = w0 * mid[k] + w4 * mid[k + 2]
                + w1 * dn[k]  + w2 * dn[k + 1] + w3 * dn[k + 2]
                + w7 * up[k]  + w6 * up[k + 1] + w5 * up[k + 2];
        y[k] = mid[k + 1] - s;
    }
}

// 6-float window [4c-1 .. 4c+4] in 2 VMEM ops; edge lanes fixed by selects.
__device__ __forceinline__ void load_row_g(const float* __restrict__ base,
                                           int r, int c, float* buf) {
    if (r < 0 || r >= HH) {
#pragma unroll
        for (int k = 0; k < 6; ++k) buf[k] = 0.f;
        return;
    }
    const float* p = base + (size_t)r * WW + 4 * c;
    const bool notfirst = (c > 0);
    const bool notlast = (c < TPB - 1);
    const vfloat4u a = *reinterpret_cast<const vfloat4u*>(p - (notfirst ? 1 : 0));
    const vfloat2u b = *reinterpret_cast<const vfloat2u*>(p + (notlast ? 3 : 2));
    buf[0] = notfirst ? a.x : 0.f;
    buf[1] = notfirst ? a.y : a.x;
    buf[2] = notfirst ? a.z : a.y;
    buf[3] = notfirst ? a.w : a.z;
    buf[4] = notlast ? b.x : b.y;
    buf[5] = notlast ? b.y : 0.f;
}

// ---------------- pass 1: pure-read stencil -> stats partials ----------------
__global__ __launch_bounds__(TPB) void ltpe_stats(const float* __restrict__ x,
                                                  float* __restrict__ partials) {
    const int img = blockIdx.x / NBLK1;
    const int blk = blockIdx.x % NBLK1;
    const int c = threadIdx.x;
    const float* base = x + (size_t)img * HW;
    const int r0 = blk * RPB1;

    // ring-8 row pipeline, depth 4: prologue issues rows r0-1 .. r0+5
    float buf[8][6];
#pragma unroll
    for (int j = 0; j < 7; ++j)
        load_row_g(base, r0 - 1 + j, c, buf[j]);

    float s = 0.f, ss = 0.f;
#pragma unroll
    for (int i = 0; i < RPB1; ++i) {
        const int r = r0 + i;
        float y[4];
        compute_y(buf[i & 7], buf[(i + 1) & 7], buf[(i + 2) & 7], y);
#pragma unroll
        for (int k = 0; k < 4; ++k) { s += y[k]; ss = fmaf(y[k], y[k], ss); }
        if (i + 6 <= RPB1)  // row r+6 needed through row r0+RPB1
            load_row_g(base, r + 6, c, buf[(i + 7) & 7]);
    }

    // block reduction: wave64 shuffle, then LDS across 4 waves
#pragma unroll
    for (int off = 32; off > 0; off >>= 1) {
        s += __shfl_down(s, off);
        ss += __shfl_down(ss, off);
    }
    __shared__ float sh[8];
    const int wave = threadIdx.x >> 6;
    const int lane = threadIdx.x & 63;
    if (lane == 0) { sh[wave] = s; sh[4 + wave] = ss; }
    __syncthreads();
    if (threadIdx.x == 0) {
        partials[img * NBLK1 + blk] = sh[0] + sh[1] + sh[2] + sh[3];
        partials[NIMG * NBLK1 + img * NBLK1 + blk] = sh[4] + sh[5] + sh[6] + sh[7];
    }
}

// ------------- pass 2: reduce head + stencil recompute + nt store -------------
__global__ __launch_bounds__(TPB) void ltpe_norm(const float* __restrict__ x,
                                                 const float* __restrict__ partials,
                                                 float* __restrict__ out) {
    const int img = blockIdx.x / NBLK2;
    const int blk = blockIdx.x % NBLK2;
    const int c = threadIdx.x;
    const float* base = x + (size_t)img * HW;
    const int r0 = blk * RPB2;

    // issue prologue loads first so the reduce hides under them
    float buf[8][6];
#pragma unroll
    for (int j = 0; j < 7; ++j)
        load_row_g(base, r0 - 1 + j, c, buf[j]);

    // redundant per-block final reduce of this image's 64 partials (one wave)
    __shared__ float sh_stats[2];
    if (threadIdx.x < 64) {
        const int lane = threadIdx.x;
        double S = (double)partials[img * NBLK1 + lane];
        double SS = (double)partials[NIMG * NBLK1 + img * NBLK1 + lane];
#pragma unroll
        for (int off = 32; off > 0; off >>= 1) {
            S += __shfl_down(S, off);
            SS += __shfl_down(SS, off);
        }
        if (lane == 0) {
            const double N = (double)HW;
            const double m = S / N;
            const double var = SS / N - m * m;
            sh_stats[0] = (float)m;
            sh_stats[1] = (float)(1.0 / sqrt(var + 4e-5)); // 4*eps folds the 0.5
        }
    }
    __syncthreads();
    const float mean = sh_stats[0];
    const float scale = sh_stats[1];

    float* obase = out + (size_t)img * HW;

#pragma unroll
    for (int i = 0; i < RPB2; ++i) {
        const int r = r0 + i;
        float y[4];
        compute_y(buf[i & 7], buf[(i + 1) & 7], buf[(i + 2) & 7], y);
        // issue the prefetch BEFORE the store so the load enters the queue first
        if (i + 6 <= RPB2)
            load_row_g(base, r + 6, c, buf[(i + 7) & 7]);
        vfloat4 o;
        o.x = (y[0] - mean) * scale;
        o.y = (y[1] - mean) * scale;
        o.z = (y[2] - mean) * scale;
        o.w = (y[3] - mean) * scale;
        __builtin_nontemporal_store(
            o, reinterpret_cast<vfloat4*>(obase + (size_t)r * WW) + c);
    }
}

extern "C" void kernel_launch(void* const* d_in, const int* in_sizes, int n_in,
                              void* d_out, int out_size, void* d_ws, size_t ws_size,
                              hipStream_t stream) {
    const float* x = (const float*)d_in[0];
    float* out = (float*)d_out;
    float* partials = (float*)d_ws; // [NIMG*NBLK1 sums][NIMG*NBLK1 sumsqs]

    ltpe_stats<<<NIMG * NBLK1, TPB, 0, stream>>>(x, partials);
    ltpe_norm<<<NIMG * NBLK2, TPB, 0, stream>>>(x, partials, out);
}

// Round 18
// 69.613 us; speedup vs baseline: 1.3076x; 1.0101x over previous
//
#include <hip/hip_runtime.h>

// LTPE: y(p) = x(p) - sum_j w_j * x(p + off_j), zero-padded borders,
// then instance-norm over HxW per image: (y - mean) * rsqrt(var + 4e-5).
// (The reference's out = 0.5*y + 0.5; instance norm is affine-invariant,
//  with eps folding 1e-5 -> 4e-5.)
//
// FINAL: round-11 measured-best configuration (69.7us), restored.
// Structure: two plain kernels. Pass 1 = pure-read stencil + stats
// partials (NBLK1=64 -> 2048 blocks for residency; no stores in the
// K-loop). Pass 2 = per-block redundant reduce (hidden under the initial
// row loads) + stencil recompute + nt streaming store (NBLK2=32).
// Session ledger (17 rounds): fusion x3 (coop grid.sync 197us,
// acquire-poll 171us, relaxed-RMW 144us) all convoy-bound; bf16-y cache
// 92us; stencil->out + in-place norm 91us (cold stencil+store class is
// stall-bound at 2.7 TB/s); shuffle-halos +11us; forced min-waves spills
// (108us); nt-vs-plain, 2-op loader, de-interleave, depth-4 all null.
// Pass 2 runs at ~6.5 TB/s combined = the D2D copy ceiling (m13: 6.29);
// pass 1 within ~25% of pure-read ceiling with all levers null ->
// practical roofline for this op on MI355X.

#define HH 1024
#define WW 1024
#define HW (HH * WW)
#define NIMG 32
#define NBLK1 64                 // pass-1 blocks per image (pure read)
#define RPB1 (HH / NBLK1)        // 16 rows per block
#define NBLK2 32                 // pass-2 blocks per image (read + nt store)
#define RPB2 (HH / NBLK2)        // 32 rows per block
#define TPB 256                  // = WW/4 float4 columns per row

typedef float vfloat4 __attribute__((ext_vector_type(4)));

// weights: j=0..7 -> 2^j/255, offsets (dy,dx):
// j0 (0,-1), j1 (1,-1), j2 (1,0), j3 (1,1), j4 (0,1), j5 (-1,1), j6 (-1,0), j7 (-1,-1)
__device__ __forceinline__ void compute_y(const float* up, const float* mid,
                                          const float* dn, float* y) {
    const float w0 = 1.f / 255.f,  w1 = 2.f / 255.f,  w2 = 4.f / 255.f,
                w3 = 8.f / 255.f,  w4 = 16.f / 255.f, w5 = 32.f / 255.f,
                w6 = 64.f / 255.f, w7 = 128.f / 255.f;
#pragma unroll
    for (int k = 0; k < 4; ++k) {
        float s = w0 * mid[k] + w4 * mid[k + 2]
                + w1 * dn[k]  + w2 * dn[k + 1] + w3 * dn[k + 2]
                + w7 * up[k]  + w6 * up[k + 1] + w5 * up[k + 2];
        y[k] = mid[k + 1] - s;
    }
}

// buf[0]=left halo, buf[1..4]=vfloat4, buf[5]=right halo; zeros out of range
__device__ __forceinline__ void load_row_g(const float* __restrict__ base,
                                           int r, int c, float* buf) {
    if (r < 0 || r >= HH) {
#pragma unroll
        for (int k = 0; k < 6; ++k) buf[k] = 0.f;
        return;
    }
    const float* row = base + (size_t)r * WW;
    const vfloat4 v = reinterpret_cast<const vfloat4*>(row)[c];
    buf[0] = (c > 0) ? row[4 * c - 1] : 0.f;
    buf[1] = v.x; buf[2] = v.y; buf[3] = v.z; buf[4] = v.w;
    buf[5] = (c < TPB - 1) ? row[4 * c + 4] : 0.f;
}

// ---------------- pass 1: pure-read stencil -> stats partials ----------------
__global__ __launch_bounds__(TPB) void ltpe_stats(const float* __restrict__ x,
                                                  float* __restrict__ partials) {
    const int img = blockIdx.x / NBLK1;
    const int blk = blockIdx.x % NBLK1;
    const int c = threadIdx.x;
    const float* base = x + (size_t)img * HW;
    const int r0 = blk * RPB1;

    // rolling 4-row register pipeline (2-deep prefetch), fully unrolled
    float buf[4][6];
    load_row_g(base, r0 - 1, c, buf[0]);
    load_row_g(base, r0,     c, buf[1]);
    load_row_g(base, r0 + 1, c, buf[2]);
    load_row_g(base, r0 + 2, c, buf[3]);

    float s = 0.f, ss = 0.f;
#pragma unroll
    for (int i = 0; i < RPB1; ++i) {
        const int r = r0 + i;
        float y[4];
        compute_y(buf[i & 3], buf[(i + 1) & 3], buf[(i + 2) & 3], y);
#pragma unroll
        for (int k = 0; k < 4; ++k) { s += y[k]; ss = fmaf(y[k], y[k], ss); }
        if (i + 2 < RPB1)  // row r+3 serves as dn in iter i+2
            load_row_g(base, r + 3, c, buf[i & 3]);
    }

    // block reduction: wave64 shuffle, then LDS across 4 waves
#pragma unroll
    for (int off = 32; off > 0; off >>= 1) {
        s += __shfl_down(s, off);
        ss += __shfl_down(ss, off);
    }
    __shared__ float sh[8];
    const int wave = threadIdx.x >> 6;
    const int lane = threadIdx.x & 63;
    if (lane == 0) { sh[wave] = s; sh[4 + wave] = ss; }
    __syncthreads();
    if (threadIdx.x == 0) {
        partials[img * NBLK1 + blk] = sh[0] + sh[1] + sh[2] + sh[3];
        partials[NIMG * NBLK1 + img * NBLK1 + blk] = sh[4] + sh[5] + sh[6] + sh[7];
    }
}

// ------------- pass 2: reduce head + stencil recompute + nt store -------------
__global__ __launch_bounds__(TPB) void ltpe_norm(const float* __restrict__ x,
                                                 const float* __restrict__ partials,
                                                 float* __restrict__ out) {
    const int img = blockIdx.x / NBLK2;
    const int blk = blockIdx.x % NBLK2;
    const int c = threadIdx.x;
    const float* base = x + (size_t)img * HW;
    const int r0 = blk * RPB2;

    // issue initial pipeline loads first so the reduce hides under them
    float buf[4][6];
    load_row_g(base, r0 - 1, c, buf[0]);
    load_row_g(base, r0,     c, buf[1]);
    load_row_g(base, r0 + 1, c, buf[2]);
    load_row_g(base, r0 + 2, c, buf[3]);

    // redundant per-block final reduce of this image's 64 partials (one wave)
    __shared__ float sh_stats[2];
    if (threadIdx.x < 64) {
        const int lane = threadIdx.x;
        double S = (double)partials[img * NBLK1 + lane];
        double SS = (double)partials[NIMG * NBLK1 + img * NBLK1 + lane];
#pragma unroll
        for (int off = 32; off > 0; off >>= 1) {
            S += __shfl_down(S, off);
            SS += __shfl_down(SS, off);
        }
        if (lane == 0) {
            const double N = (double)HW;
            const double m = S / N;
            const double var = SS / N - m * m;
            sh_stats[0] = (float)m;
            sh_stats[1] = (float)(1.0 / sqrt(var + 4e-5)); // 4*eps folds the 0.5
        }
    }
    __syncthreads();
    const float mean = sh_stats[0];
    const float scale = sh_stats[1];

    float* obase = out + (size_t)img * HW;

#pragma unroll
    for (int i = 0; i < RPB2; ++i) {
        const int r = r0 + i;
        float y[4];
        compute_y(buf[i & 3], buf[(i + 1) & 3], buf[(i + 2) & 3], y);
        vfloat4 o;
        o.x = (y[0] - mean) * scale;
        o.y = (y[1] - mean) * scale;
        o.z = (y[2] - mean) * scale;
        o.w = (y[3] - mean) * scale;
        // nt streaming store for the 128 MB output
        __builtin_nontemporal_store(
            o, reinterpret_cast<vfloat4*>(obase + (size_t)r * WW) + c);
        if (i + 2 < RPB2)  // row r+3 serves as dn in iter i+2
            load_row_g(base, r + 3, c, buf[i & 3]);
    }
}

extern "C" void kernel_launch(void* const* d_in, const int* in_sizes, int n_in,
                              void* d_out, int out_size, void* d_ws, size_t ws_size,
                              hipStream_t stream) {
    const float* x = (const float*)d_in[0];
    float* out = (float*)d_out;
    float* partials = (float*)d_ws; // [NIMG*NBLK1 sums][NIMG*NBLK1 sumsqs]

    ltpe_stats<<<NIMG * NBLK1, TPB, 0, stream>>>(x, partials);
    ltpe_norm<<<NIMG * NBLK2, TPB, 0, stream>>>(x, partials, out);
}